// Round 6
// baseline (2572.420 us; speedup 1.0000x reference)
//
#include <hip/hip_runtime.h>

#define BB 256
#define TT 2048
#define SS 32
#define NN 19
#define NCLASS 10
#define NUNFOLD 6
#define EPSV 1e-8f
#define LOG2E 1.4426950408889634f

typedef float f32x2 __attribute__((ext_vector_type(2)));

__device__ __forceinline__ f32x2 pk_fma(f32x2 a, f32x2 b, f32x2 c)
{
#if __has_builtin(__builtin_elementwise_fma)
    return __builtin_elementwise_fma(a, b, c);
#else
    return (f32x2){fmaf(a.x, b.x, c.x), fmaf(a.y, b.y, c.y)};
#endif
}
__device__ __forceinline__ f32x2 splat2(float s) { return (f32x2){s, s}; }

// ---------------------------------------------------------------------------
// Phase 1: sensory precompute.  Thread = (t,b) computing ALL 19 outputs.
// Folded params (P, -Q, W, A) staged in LDS once per block -> x read exactly
// once (no 19x re-read), ~50 VGPR (no spills), lane-uniform LDS broadcasts.
// ---------------------------------------------------------------------------
__global__ void __launch_bounds__(256)
ltc_sens_kernel(const float* __restrict__ x,
                const float* __restrict__ iw,
                const float* __restrict__ ib,
                const float* __restrict__ smu,
                const float* __restrict__ ssig,
                const float* __restrict__ sw,
                const float* __restrict__ serev,
                const int* __restrict__ smask,
                float* __restrict__ sens,
                int t0, int tc)
{
    __shared__ float4 pq[SS * NN];            // {P, Qn, W, A} per (s,j)
    int tid = threadIdx.x;
    for (int idx = tid; idx < SS * NN; idx += 256) {
        int s = idx / NN;                     // idx = s*NN + j
        float sg = ssig[idx] * LOG2E;
        float P  = sg * smu[idx] - sg * ib[s];
        float Qn = -sg * iw[s];
        float wm = sw[idx] * (float)smask[idx];
        pq[idx] = make_float4(P, Qn, wm, wm * serev[idx]);
    }
    __syncthreads();

    long gid = (long)blockIdx.x * 256 + tid;
    if (gid >= (long)tc * BB) return;
    int trel = (int)(gid % tc);               // t fast -> coalesced-ish x reads
    int b    = (int)(gid / tc);
    int t    = t0 + trel;

    float xs[SS];
    const float4* xr4 = (const float4*)(x + ((long)b * TT + t) * SS);
#pragma unroll
    for (int q = 0; q < SS / 4; q++) {
        float4 v4 = xr4[q];
        xs[4 * q + 0] = v4.x; xs[4 * q + 1] = v4.y;
        xs[4 * q + 2] = v4.z; xs[4 * q + 3] = v4.w;
    }

    float* o = sens + ((long)trel * BB + b) * (2 * NN);
    for (int j = 0; j < NN; j++) {
        f32x2 nd = {0.f, 0.f};
#pragma unroll 4
        for (int s = 0; s < SS; s += 2) {
            float4 c0 = pq[s * NN + j];
            float4 c1 = pq[(s + 1) * NN + j];
            float e0 = __builtin_amdgcn_exp2f(fmaf(c0.y, xs[s], c0.x));
            float e1 = __builtin_amdgcn_exp2f(fmaf(c1.y, xs[s + 1], c1.x));
            f32x2 tv = (f32x2){e0, e1} + 1.0f;
            float rD = __builtin_amdgcn_rcpf(tv.x * tv.y);
            f32x2 aw0 = {c0.w, c0.z};         // {A, W}
            f32x2 aw1 = {c1.w, c1.z};
            f32x2 npq = pk_fma(aw1, splat2(tv.x), aw0 * splat2(tv.y));
            nd = pk_fma(npq, splat2(rD), nd);
        }
        o[j]      = nd.x;
        o[NN + j] = nd.y;
    }
}

// ---------------------------------------------------------------------------
template <int CTRL>
__device__ __forceinline__ float dpp_shl(float x)
{
    return __int_as_float(__builtin_amdgcn_update_dpp(
        0, __float_as_int(x), CTRL, 0xf, 0xf, true));
}

__device__ __forceinline__ float bperm(int addr4, float v)
{
    return __int_as_float(__builtin_amdgcn_ds_bpermute(addr4, __float_as_int(v)));
}

// leader lane of pre-neuron i (rows 2,3 offset +1 => all 19 leaders in
// distinct LDS banks -> conflict-free bpermute broadcast)
__device__ __forceinline__ int lead_lane(int i)
{
    int rw = i / 5;
    return 16 * rw + 3 * (i % 5) + (rw >= 2 ? 1 : 0);
}

// ---------------------------------------------------------------------------
// Templated scan main loop.  KU = wave-max slots/lane.  Packed f32x2 math:
// (pn,pd) accumulate in one register pair via v_pk_fma; dummy slots use
// sb2=-128 -> e=0 exactly, so padded pairs are numerically exact.
// ---------------------------------------------------------------------------
template <int KU>
__device__ __forceinline__ void run_scan(
    int lane, int jc, bool pad, int r,
    const float (&sg2)[8], const float (&sb2)[8],
    const float (&Aa)[8], const float (&Wm)[8], const int (&src4)[8],
    float cmt, float glvl, float cgl, float ow0, float ob0,
    const float* __restrict__ sens, float* __restrict__ outbuf,
    float* __restrict__ vstate, int b, int t0, int tc, int initv)
{
    constexpr int NP2 = (KU + 1) / 2;

    // pack loop-invariants
    f32x2 SG[NP2], SB[NP2], AW0[NP2], AW1[NP2];
#pragma unroll
    for (int p = 0; p < NP2; p++) {
        SG[p]  = (f32x2){sg2[2 * p], sg2[2 * p + 1]};
        SB[p]  = (f32x2){sb2[2 * p], sb2[2 * p + 1]};
        AW0[p] = (f32x2){Aa[2 * p],  Wm[2 * p]};
        AW1[p] = (f32x2){Aa[2 * p + 1], Wm[2 * p + 1]};
    }
    f32x2 vip[NP2];
#pragma unroll
    for (int p = 0; p < NP2; p++) vip[p] = (f32x2){0.f, 0.f};

    float v = initv ? 0.f : vstate[b * NN + jc];
    const float* sp0 = sens + (long)b * (2 * NN);
    float sn = sp0[jc], sd = sp0[NN + jc];

    for (int t = 0; t < tc; t++) {
        float sn_nx = sn, sd_nx = sd;
        if (t + 1 < tc) {
            const float* spn = sens + ((long)(t + 1) * BB + b) * (2 * NN);
            sn_nx = spn[jc]; sd_nx = spn[NN + jc];
        }
        float nbase = glvl + sn, dbase = cgl + sd;

#pragma unroll
        for (int u = 0; u < NUNFOLD; u++) {
            // broadcast leader v's (conflict-free bpermute)
#pragma unroll
            for (int p = 0; p < NP2; p++) {
                vip[p].x = bperm(src4[2 * p], v);
                if (2 * p + 1 < KU) vip[p].y = bperm(src4[2 * p + 1], v);
            }
            float n = fmaf(cmt, v, nbase);

            f32x2 evp[NP2];
#pragma unroll
            for (int p = 0; p < NP2; p++) {
                f32x2 arg = pk_fma(SG[p], vip[p], SB[p]);
                evp[p].x = __builtin_amdgcn_exp2f(arg.x);
                evp[p].y = __builtin_amdgcn_exp2f(arg.y);
            }

            f32x2 pnd = {0.f, 0.f};
#pragma unroll
            for (int p = 0; p < NP2; p++) {
                f32x2 tv = evp[p] + 1.0f;
                float rD = __builtin_amdgcn_rcpf(tv.x * tv.y);
                f32x2 npq = pk_fma(AW1[p], splat2(tv.x), AW0[p] * splat2(tv.y));
                pnd = pk_fma(npq, splat2(rD), pnd);
            }

            float pn = pnd.x, pd = pnd.y;
            // 3-lane DPP reduce: triple base lane gets the full sum
            pn = pn + dpp_shl<0x101>(pn) + dpp_shl<0x102>(pn);
            pd = pd + dpp_shl<0x101>(pd) + dpp_shl<0x102>(pd);

            // all lanes update; only leader lanes are ever read (bperm/store)
            v = (n + pn) * __builtin_amdgcn_rcpf(dbase + pd);
        }
        if (lane == 0) outbuf[(long)b * TT + (t0 + t)] = fmaf(v, ow0, ob0);
        sn = sn_nx; sd = sd_nx;
    }
    if (!pad && r == 0) vstate[b * NN + jc] = v;
}

// ---------------------------------------------------------------------------
// Phase 2 kernel: prologue builds balanced sparse synapse lists (mask ~50%
// zero), then dispatches to the KU-templated loop (wave-uniform mask).
// ---------------------------------------------------------------------------
__global__ void __launch_bounds__(64, 1)
ltc_scan_kernel(const float* __restrict__ mu,  const float* __restrict__ sigma,
                const float* __restrict__ w,   const float* __restrict__ erev,
                const int* __restrict__ mask,
                const float* __restrict__ gleak, const float* __restrict__ vleak,
                const float* __restrict__ cm,
                const float* __restrict__ ow,  const float* __restrict__ ob,
                const float* __restrict__ sens, float* __restrict__ outbuf,
                float* __restrict__ vstate, int t0, int tc, int initv)
{
    int b    = blockIdx.x;
    int lane = threadIdx.x;
    int row  = lane >> 4;
    int pos  = lane & 15;
    int off  = (row >= 2) ? 1 : 0;
    int posr = pos - off;                       // row>=2: pos 0 is pad
    int jq   = (posr < 0) ? 5 : posr / 3;       // 5 => pad
    int rr   = (posr < 0) ? 0 : posr - 3 * jq;
    int j    = row * 5 + jq;
    bool pad = (jq >= 5) || (j >= NN);
    int jc   = pad ? 0 : j;
    int r    = pad ? 0 : rr;

    // balanced sparse slot lists: the a-th active pre-neuron of column j goes
    // to lane r = a%3, slot a/3.  Dummy slots: sb2=-128 -> e=0 (exact pad).
    float sg2[8], sb2[8], Aa[8], Wm[8];
    int src4[8];
    int used = 0;
#pragma unroll
    for (int s = 0; s < 8; s++) {
        int target = 3 * s + r;
        int ii = -1, a = 0;
        for (int i = 0; i < NN; i++) {
            if (mask[i * NN + jc] != 0) {
                if (a == target) ii = i;
                a++;
            }
        }
        bool ok = (ii >= 0) && !pad;
        int iu  = ok ? ii : 0;
        int idx = iu * NN + jc;
        float sgv = sigma[idx];
        float wmm = ok ? w[idx] : 0.f;          // mask[idx]==1 when ok
        sg2[s] = ok ? (-LOG2E * sgv) : 0.f;
        sb2[s] = ok ? (LOG2E * sgv * mu[idx]) : -128.f;
        Aa[s]  = wmm * erev[idx];
        Wm[s]  = wmm;
        src4[s] = lead_lane(iu) << 2;
        if (ok) used = s + 1;
    }

    // wave-max of used slots (prologue-only shuffles)
    int km = used;
#pragma unroll
    for (int o = 1; o < 64; o <<= 1) {
        int other = __shfl_xor(km, o, 64);
        km = km > other ? km : other;
    }

    float cmt   = cm[jc] * (float)NUNFOLD;
    float gl    = gleak[jc];
    float glvl  = gl * vleak[jc];
    float cgl   = cmt + gl + EPSV;
    float ow0 = ow[0], ob0 = ob[0];

    if (km <= 3)
        run_scan<3>(lane, jc, pad, r, sg2, sb2, Aa, Wm, src4, cmt, glvl, cgl,
                    ow0, ob0, sens, outbuf, vstate, b, t0, tc, initv);
    else if (km == 4)
        run_scan<4>(lane, jc, pad, r, sg2, sb2, Aa, Wm, src4, cmt, glvl, cgl,
                    ow0, ob0, sens, outbuf, vstate, b, t0, tc, initv);
    else if (km == 5)
        run_scan<5>(lane, jc, pad, r, sg2, sb2, Aa, Wm, src4, cmt, glvl, cgl,
                    ow0, ob0, sens, outbuf, vstate, b, t0, tc, initv);
    else if (km == 6)
        run_scan<6>(lane, jc, pad, r, sg2, sb2, Aa, Wm, src4, cmt, glvl, cgl,
                    ow0, ob0, sens, outbuf, vstate, b, t0, tc, initv);
    else
        run_scan<7>(lane, jc, pad, r, sg2, sb2, Aa, Wm, src4, cmt, glvl, cgl,
                    ow0, ob0, sens, outbuf, vstate, b, t0, tc, initv);
}

// ---------------------------------------------------------------------------
// Phase 3: FC head.  One wave per (b, c).
// ---------------------------------------------------------------------------
__global__ void ltc_fc_kernel(const float* __restrict__ outbuf,
                              const float* __restrict__ fcw,
                              const float* __restrict__ fcb,
                              float* __restrict__ out)
{
    int bc = blockIdx.x;
    int b = bc / NCLASS;
    int c = bc % NCLASS;
    const float* xr = outbuf + (long)b * TT;
    const float* wr = fcw + (long)c * TT;
    float acc = 0.f;
    for (int t = threadIdx.x; t < TT; t += 64)
        acc = fmaf(xr[t], wr[t], acc);
#pragma unroll
    for (int off = 32; off > 0; off >>= 1)
        acc += __shfl_down(acc, off, 64);
    if (threadIdx.x == 0) out[bc] = acc + fcb[c];
}

// ---------------------------------------------------------------------------
extern "C" void kernel_launch(void* const* d_in, const int* in_sizes, int n_in,
                              void* d_out, int out_size, void* d_ws, size_t ws_size,
                              hipStream_t stream)
{
    const float* x     = (const float*)d_in[0];
    const float* iw    = (const float*)d_in[1];
    const float* ib    = (const float*)d_in[2];
    const float* smu   = (const float*)d_in[3];
    const float* ssig  = (const float*)d_in[4];
    const float* sw    = (const float*)d_in[5];
    const float* serev = (const float*)d_in[6];
    const float* mu    = (const float*)d_in[7];
    const float* sigma = (const float*)d_in[8];
    const float* w     = (const float*)d_in[9];
    const float* erev  = (const float*)d_in[10];
    const float* gleak = (const float*)d_in[11];
    const float* vleak = (const float*)d_in[12];
    const float* cm    = (const float*)d_in[13];
    const float* ow    = (const float*)d_in[14];
    const float* ob    = (const float*)d_in[15];
    const float* fcw   = (const float*)d_in[16];
    const float* fcb   = (const float*)d_in[17];
    const int* smask   = (const int*)d_in[18];
    const int* mask    = (const int*)d_in[19];
    float* out = (float*)d_out;

    // ws layout: [outbuf: B*T f32][vstate: B*N f32][sens: Tc*B*2N f32]
    float* outbuf = (float*)d_ws;
    float* vstate = outbuf + (long)BB * TT;
    float* sens   = vstate + (long)BB * NN;

    size_t fixed = ((size_t)BB * TT + (size_t)BB * NN) * sizeof(float);
    long avail = (long)ws_size - (long)fixed;
    long per_step = (long)BB * 2 * NN * sizeof(float);
    int Tc = (int)(avail / per_step);
    if (Tc > TT) Tc = TT;
    if (Tc < 1)  Tc = 1;

    for (int t0 = 0; t0 < TT; t0 += Tc) {
        int tc = (TT - t0 < Tc) ? (TT - t0) : Tc;
        long total = (long)tc * BB;
        int blocks = (int)((total + 255) / 256);
        ltc_sens_kernel<<<blocks, 256, 0, stream>>>(x, iw, ib, smu, ssig, sw,
                                                    serev, smask, sens, t0, tc);
        ltc_scan_kernel<<<BB, 64, 0, stream>>>(mu, sigma, w, erev, mask, gleak,
                                               vleak, cm, ow, ob, sens, outbuf,
                                               vstate, t0, tc, t0 == 0 ? 1 : 0);
    }
    ltc_fc_kernel<<<BB * NCLASS, 64, 0, stream>>>(outbuf, fcw, fcb, out);
}